// Round 1
// baseline (1341.183 us; speedup 1.0000x reference)
//
#include <hip/hip_runtime.h>

#define N_ROWS 65536
#define C_CLUST 512
#define D_DIM 256

// ---- workspace layout (float-index units) ----
#define WS_DICTT   0          // 256*512 = 131072 floats
#define WS_DSQ     131072     // 512
#define WS_XSQ     131584     // 65536
#define WS_CS      197120     // 512
#define WS_DCY     197632     // 512
#define WS_ISUM    198144     // 512*256 = 131072
#define WS_COUNTS  329216     // 512 uint
#define WS_OFFSETS 329728     // 513 uint
#define WS_FILL    330752     // 512 uint
#define WS_ROWLIST 331264     // 262144 uint
// total ~593408 floats = 2.27 MB

// ---- output layout (float-index units) ----
#define OUT_GEMB 0
#define OUT_TOPK 16777216
#define OUT_DICT 17039360
#define OUT_CSS  17170432
#define OUT_CV   17170944
#define OUT_CNUM 17302016

#define BM 128
#define BN 128
#define BK 16

// ---------- K-zero: zero counters ----------
__global__ void zero_k(unsigned* counts, unsigned* fill) {
    int t = blockIdx.x * blockDim.x + threadIdx.x;
    if (t < 512) { counts[t] = 0u; fill[t] = 0u; }
}

// ---------- K0: dict transpose + ||d||^2 ----------
__global__ void prep_dict(const float* __restrict__ dic, float* __restrict__ ws) {
    int c = blockIdx.x, k = threadIdx.x;
    float v = dic[c * D_DIM + k];
    ws[WS_DICTT + k * C_CLUST + c] = v;
    __shared__ float red[256];
    red[k] = v * v;
    __syncthreads();
    for (int s = 128; s > 0; s >>= 1) {
        if (k < s) red[k] += red[k + s];
        __syncthreads();
    }
    if (k == 0) ws[WS_DSQ + c] = red[0];
}

// ---------- K0b: ||x||^2 per row ----------
__global__ void row_sq(const float* __restrict__ x, float* __restrict__ ws) {
    int row = blockIdx.x, k = threadIdx.x;
    float v = x[row * D_DIM + k];
    __shared__ float red[256];
    red[k] = v * v;
    __syncthreads();
    for (int s = 128; s > 0; s >>= 1) {
        if (k < s) red[k] += red[k + s];
        __syncthreads();
    }
    if (k == 0) ws[WS_XSQ + row] = red[0];
}

// ---------- K1: fused GEMM (distances) + top-4 + histogram ----------
__global__ __launch_bounds__(256, 2) void gemm_topk(
    const float* __restrict__ x, const float* __restrict__ ws,
    float* __restrict__ out_topk, unsigned* __restrict__ counts)
{
    extern __shared__ float smem[];            // 16512 floats Stile / As+Bs union
    unsigned* hist = (unsigned*)(smem + 16512); // 512 uints
    float* As = smem;          // [BK][BM]
    float* Bs = smem + 2048;   // [BK][BN]

    const int tid = threadIdx.x;
    const int tx = tid & 15, ty = tid >> 4;
    const int rowBase = blockIdx.x * BM;
    const float* dictT = ws + WS_DICTT;
    const float* dsq = ws + WS_DSQ;
    const float* xsq = ws + WS_XSQ;

    for (int h = tid; h < 512; h += 256) hist[h] = 0u;

    float td0 = 3.4e38f, td1 = 3.4e38f, td2 = 3.4e38f, td3 = 3.4e38f;
    int ti0 = -1, ti1 = -1, ti2 = -1, ti3 = -1;

    for (int cc = 0; cc < C_CLUST / BN; ++cc) {
        float acc[8][8];
        #pragma unroll
        for (int i = 0; i < 8; ++i)
            #pragma unroll
            for (int j = 0; j < 8; ++j) acc[i][j] = 0.f;

        for (int kb = 0; kb < D_DIM / BK; ++kb) {
            __syncthreads();
            // stage A (transposed into LDS): 128 rows x 16 k
            #pragma unroll
            for (int i = 0; i < 2; ++i) {
                int q = tid + i * 256;       // 512 float4s
                int r = q >> 2;
                int kk = (q & 3) << 2;
                const float4 v = *reinterpret_cast<const float4*>(
                    &x[(rowBase + r) * D_DIM + kb * BK + kk]);
                As[(kk + 0) * BM + r] = v.x;
                As[(kk + 1) * BM + r] = v.y;
                As[(kk + 2) * BM + r] = v.z;
                As[(kk + 3) * BM + r] = v.w;
            }
            // stage B: 16 k x 128 clusters (dictT is [D][C])
            #pragma unroll
            for (int i = 0; i < 2; ++i) {
                int q = tid + i * 256;
                int k = q >> 5;
                int c4 = (q & 31) << 2;
                *reinterpret_cast<float4*>(&Bs[k * BN + c4]) =
                    *reinterpret_cast<const float4*>(
                        &dictT[(kb * BK + k) * C_CLUST + cc * BN + c4]);
            }
            __syncthreads();
            #pragma unroll
            for (int k = 0; k < BK; ++k) {
                float a[8], b[8];
                float4 t0 = *reinterpret_cast<const float4*>(&As[k * BM + ty * 8]);
                float4 t1 = *reinterpret_cast<const float4*>(&As[k * BM + ty * 8 + 4]);
                float4 u0 = *reinterpret_cast<const float4*>(&Bs[k * BN + tx * 8]);
                float4 u1 = *reinterpret_cast<const float4*>(&Bs[k * BN + tx * 8 + 4]);
                a[0]=t0.x; a[1]=t0.y; a[2]=t0.z; a[3]=t0.w;
                a[4]=t1.x; a[5]=t1.y; a[6]=t1.z; a[7]=t1.w;
                b[0]=u0.x; b[1]=u0.y; b[2]=u0.z; b[3]=u0.w;
                b[4]=u1.x; b[5]=u1.y; b[6]=u1.z; b[7]=u1.w;
                #pragma unroll
                for (int i = 0; i < 8; ++i)
                    #pragma unroll
                    for (int j = 0; j < 8; ++j)
                        acc[i][j] = fmaf(a[i], b[j], acc[i][j]);
            }
        }
        __syncthreads();
        // epilogue: S = (x^2 + d^2) - 2*dot  (match np association; no fma)
        {
            float ds[8];
            #pragma unroll
            for (int j = 0; j < 8; ++j) ds[j] = dsq[cc * BN + tx * 8 + j];
            #pragma unroll
            for (int i = 0; i < 8; ++i) {
                float xs = xsq[rowBase + ty * 8 + i];
                #pragma unroll
                for (int j = 0; j < 8; ++j) {
                    float v = __fsub_rn(__fadd_rn(xs, ds[j]),
                                        __fmul_rn(2.0f, acc[i][j]));
                    smem[(ty * 8 + i) * 129 + tx * 8 + j] = v;
                }
            }
        }
        __syncthreads();
        // top-4 merge: thread t owns row t (strict <, increasing idx => top_k ties)
        if (tid < BM) {
            const float* srow = &smem[tid * 129];
            #pragma unroll 4
            for (int c = 0; c < BN; ++c) {
                float v = srow[c];
                int idx = cc * BN + c;
                if (v < td3) {
                    if (v < td2) {
                        td3 = td2; ti3 = ti2;
                        if (v < td1) {
                            td2 = td1; ti2 = ti1;
                            if (v < td0) { td1 = td0; ti1 = ti0; td0 = v; ti0 = idx; }
                            else { td1 = v; ti1 = idx; }
                        } else { td2 = v; ti2 = idx; }
                    } else { td3 = v; ti3 = idx; }
                }
            }
        }
        __syncthreads();  // protect Stile until everyone finished scanning
    }

    if (tid < BM) {
        int r = rowBase + tid;
        out_topk[r * 4 + 0] = (float)ti0;
        out_topk[r * 4 + 1] = (float)ti1;
        out_topk[r * 4 + 2] = (float)ti2;
        out_topk[r * 4 + 3] = (float)ti3;
        atomicAdd(&hist[ti0], 1u);
        atomicAdd(&hist[ti1], 1u);
        atomicAdd(&hist[ti2], 1u);
        atomicAdd(&hist[ti3], 1u);
    }
    __syncthreads();
    for (int h = tid; h < 512; h += 256) {
        unsigned v = hist[h];
        if (v) atomicAdd(&counts[h], v);
    }
}

// ---------- K2: group_emb = mean of 4 dict rows, with STE rounding ----------
__global__ void group_emb_k(const float* __restrict__ x, const float* __restrict__ dic,
                            const float* __restrict__ topk, float* __restrict__ out)
{
    int row = blockIdx.x, d = threadIdx.x;
    int i0 = (int)topk[row * 4 + 0];
    int i1 = (int)topk[row * 4 + 1];
    int i2 = (int)topk[row * 4 + 2];
    int i3 = (int)topk[row * 4 + 3];
    float g = __fadd_rn(__fadd_rn(__fadd_rn(dic[i0 * D_DIM + d],
                                            dic[i1 * D_DIM + d]),
                                  dic[i2 * D_DIM + d]),
                        dic[i3 * D_DIM + d]);
    g = __fmul_rn(g, 0.25f);
    float xv = x[row * D_DIM + d];
    out[row * D_DIM + d] = __fadd_rn(__fsub_rn(g, xv), xv);
}

// ---------- K3: exclusive prefix sum of counts ----------
__global__ void prefix_k(const unsigned* __restrict__ counts, unsigned* __restrict__ offsets) {
    __shared__ unsigned s[512];
    int t = threadIdx.x;
    unsigned my = counts[t];
    s[t] = my;
    __syncthreads();
    for (int off = 1; off < 512; off <<= 1) {
        unsigned v = (t >= off) ? s[t - off] : 0u;
        __syncthreads();
        s[t] += v;
        __syncthreads();
    }
    offsets[t] = s[t] - my;
    if (t == 511) offsets[512] = s[511];
}

// ---------- K4: scatter rows into cluster buckets ----------
__global__ void scatter_k(const float* __restrict__ topk, const unsigned* __restrict__ offsets,
                          unsigned* __restrict__ fill, unsigned* __restrict__ rowlist) {
    int row = blockIdx.x * 256 + threadIdx.x;
    #pragma unroll
    for (int k = 0; k < 4; ++k) {
        int c = (int)topk[row * 4 + k];
        unsigned p = atomicAdd(&fill[c], 1u);
        rowlist[offsets[c] + p] = (unsigned)row;
    }
}

// ---------- K5: per-cluster input sum (encodings^T @ X) ----------
__global__ void cluster_sum_k(const float* __restrict__ x, const unsigned* __restrict__ counts,
                              const unsigned* __restrict__ offsets,
                              const unsigned* __restrict__ rowlist,
                              float* __restrict__ isum) {
    int c = blockIdx.x, d = threadIdx.x;
    unsigned n = counts[c], off = offsets[c];
    float acc = 0.f;
    unsigned j = 0;
    for (; j + 8 <= n; j += 8) {
        unsigned r0 = rowlist[off + j + 0], r1 = rowlist[off + j + 1];
        unsigned r2 = rowlist[off + j + 2], r3 = rowlist[off + j + 3];
        unsigned r4 = rowlist[off + j + 4], r5 = rowlist[off + j + 5];
        unsigned r6 = rowlist[off + j + 6], r7 = rowlist[off + j + 7];
        float v0 = x[r0 * D_DIM + d], v1 = x[r1 * D_DIM + d];
        float v2 = x[r2 * D_DIM + d], v3 = x[r3 * D_DIM + d];
        float v4 = x[r4 * D_DIM + d], v5 = x[r5 * D_DIM + d];
        float v6 = x[r6 * D_DIM + d], v7 = x[r7 * D_DIM + d];
        acc += v0; acc += v1; acc += v2; acc += v3;
        acc += v4; acc += v5; acc += v6; acc += v7;
    }
    for (; j < n; ++j) {
        unsigned r = rowlist[off + j];
        acc += x[r * D_DIM + d];
    }
    isum[c * D_DIM + d] = acc;
}

// ---------- K6: sequential decay scan + css EMA + laplace ----------
__global__ void ema_scalar_k(const float* __restrict__ css_in, const float* __restrict__ cnum_in,
                             const unsigned* __restrict__ counts,
                             float* __restrict__ ws, float* __restrict__ out) {
    __shared__ float sdecay[512];
    __shared__ float sred[512];
    __shared__ float scn[512];
    __shared__ unsigned smask[512];
    int t = threadIdx.x; // 512 threads
    unsigned cnt = counts[t];
    float size = (float)cnt;
    float mask = (cnt != 0u) ? 1.f : 0.f;
    float cnum_new = __fadd_rn(cnum_in[t], mask);
    scn[t] = cnum_new;
    smask[t] = cnt;
    __syncthreads();
    if (t == 0) {
        float d = 0.99f;
        for (int c = 0; c < 512; ++c) {
            if (smask[c] != 0u && scn[c] <= 10.0f)
                d = __fmul_rn(d, scn[c]) / 10.0f;   // (decay*c)/10, IEEE div
            sdecay[c] = d;
        }
    }
    __syncthreads();
    float d = sdecay[t];
    float css = css_in[t];
    float css_new = (cnt != 0u)
        ? __fadd_rn(__fmul_rn(css, d), __fmul_rn(size, __fsub_rn(1.f, d)))
        : css;
    out[OUT_CSS + t] = css_new;
    out[OUT_CNUM + t] = cnum_new;
    sred[t] = css_new;
    __syncthreads();
    for (int s = 256; s > 0; s >>= 1) {
        if (t < s) sred[t] += sred[t + s];
        __syncthreads();
    }
    float S = sred[0];
    float cs = __fmul_rn(__fdiv_rn(__fadd_rn(css_new, 1e-5f),
                                   __fadd_rn(S, 0.00512f)), S);
    ws[WS_CS + t] = cs;
    ws[WS_DCY + t] = d;
}

// ---------- K7: cluster_value EMA + dictionary normalize ----------
__global__ void final_k(const float* __restrict__ cv_in, const float* __restrict__ ws,
                        const unsigned* __restrict__ counts, float* __restrict__ out) {
    int c = blockIdx.x, d = threadIdx.x;
    float isum = ws[WS_ISUM + c * D_DIM + d];
    float dc = ws[WS_DCY + c];
    float cs = ws[WS_CS + c];
    unsigned cnt = counts[c];
    float cv = cv_in[c * D_DIM + d];
    float cvn = (cnt != 0u)
        ? __fadd_rn(__fmul_rn(cv, dc), __fmul_rn(isum, __fsub_rn(1.f, dc)))
        : cv;
    out[OUT_CV + c * D_DIM + d] = cvn;
    out[OUT_DICT + c * D_DIM + d] = (cnt != 0u) ? __fdiv_rn(cvn, cs) : cvn;
}

extern "C" void kernel_launch(void* const* d_in, const int* in_sizes, int n_in,
                              void* d_out, int out_size, void* d_ws, size_t ws_size,
                              hipStream_t stream) {
    const float* x       = (const float*)d_in[0];
    const float* dic     = (const float*)d_in[1];
    const float* css_in  = (const float*)d_in[2];
    const float* cv_in   = (const float*)d_in[3];
    const float* cnum_in = (const float*)d_in[4];
    float* out = (float*)d_out;
    float* ws  = (float*)d_ws;
    unsigned* counts  = (unsigned*)(ws + WS_COUNTS);
    unsigned* offsets = (unsigned*)(ws + WS_OFFSETS);
    unsigned* fill    = (unsigned*)(ws + WS_FILL);
    unsigned* rowlist = (unsigned*)(ws + WS_ROWLIST);

    zero_k<<<2, 256, 0, stream>>>(counts, fill);
    prep_dict<<<C_CLUST, 256, 0, stream>>>(dic, ws);
    row_sq<<<N_ROWS, 256, 0, stream>>>(x, ws);

    size_t smem_bytes = 16512 * sizeof(float) + 512 * sizeof(unsigned);
    gemm_topk<<<N_ROWS / BM, 256, smem_bytes, stream>>>(x, ws, out + OUT_TOPK, counts);

    group_emb_k<<<N_ROWS, 256, 0, stream>>>(x, dic, out + OUT_TOPK, out + OUT_GEMB);
    prefix_k<<<1, 512, 0, stream>>>(counts, offsets);
    scatter_k<<<N_ROWS / 256, 256, 0, stream>>>(out + OUT_TOPK, offsets, fill, rowlist);
    cluster_sum_k<<<C_CLUST, 256, 0, stream>>>(x, counts, offsets, rowlist, ws + WS_ISUM);
    ema_scalar_k<<<1, 512, 0, stream>>>(css_in, cnum_in, counts, ws, out);
    final_k<<<C_CLUST, 256, 0, stream>>>(cv_in, ws, counts, out);
}

// Round 2
// 606.287 us; speedup vs baseline: 2.2121x; 2.2121x over previous
//
#include <hip/hip_runtime.h>

#define N_ROWS 65536
#define C_CLUST 512
#define D_DIM 256

// ---- workspace layout (float-index units) ----
#define WS_DICTT   0          // 256*512 = 131072 floats
#define WS_DSQ     131072     // 512
#define WS_XSQ     131584     // 65536
#define WS_CS      197120     // 512
#define WS_DCY     197632     // 512
#define WS_ISUM    198144     // 512*256 = 131072
#define WS_COUNTS  329216     // 512 uint
#define WS_OFFSETS 329728     // 513 uint
#define WS_FILL    330752     // 512 uint
#define WS_ROWLIST 331264     // 262144 uint
// total ~593408 floats = 2.27 MB

// ---- output layout (float-index units) ----
#define OUT_GEMB 0
#define OUT_TOPK 16777216
#define OUT_DICT 17039360
#define OUT_CSS  17170432
#define OUT_CV   17170944
#define OUT_CNUM 17302016

#define BM 128
#define BN 128
#define BK 16

#define RPB 128   // rowlist entries per block in cluster_sum2_k

// ---------- K-zero: zero counters + isum ----------
__global__ void zero_k(unsigned* counts, unsigned* fill, float* isum) {
    int t = blockIdx.x * blockDim.x + threadIdx.x;
    if (t < 512) { counts[t] = 0u; fill[t] = 0u; }
    if (t < C_CLUST * D_DIM) isum[t] = 0.f;
}

// ---------- K0: dict transpose + ||d||^2 ----------
__global__ void prep_dict(const float* __restrict__ dic, float* __restrict__ ws) {
    int c = blockIdx.x, k = threadIdx.x;
    float v = dic[c * D_DIM + k];
    ws[WS_DICTT + k * C_CLUST + c] = v;
    __shared__ float red[256];
    red[k] = v * v;
    __syncthreads();
    for (int s = 128; s > 0; s >>= 1) {
        if (k < s) red[k] += red[k + s];
        __syncthreads();
    }
    if (k == 0) ws[WS_DSQ + c] = red[0];
}

// ---------- K0b: ||x||^2 per row ----------
__global__ void row_sq(const float* __restrict__ x, float* __restrict__ ws) {
    int row = blockIdx.x, k = threadIdx.x;
    float v = x[row * D_DIM + k];
    __shared__ float red[256];
    red[k] = v * v;
    __syncthreads();
    for (int s = 128; s > 0; s >>= 1) {
        if (k < s) red[k] += red[k + s];
        __syncthreads();
    }
    if (k == 0) ws[WS_XSQ + row] = red[0];
}

// ---------- K1: fused GEMM (distances) + top-4 + histogram ----------
__global__ __launch_bounds__(256, 2) void gemm_topk(
    const float* __restrict__ x, const float* __restrict__ ws,
    float* __restrict__ out_topk, unsigned* __restrict__ counts)
{
    extern __shared__ float smem[];            // 16512 floats Stile / As+Bs union
    unsigned* hist = (unsigned*)(smem + 16512); // 512 uints
    float* As = smem;          // [BK][BM]
    float* Bs = smem + 2048;   // [BK][BN]

    const int tid = threadIdx.x;
    const int tx = tid & 15, ty = tid >> 4;
    const int rowBase = blockIdx.x * BM;
    const float* dictT = ws + WS_DICTT;
    const float* dsq = ws + WS_DSQ;
    const float* xsq = ws + WS_XSQ;

    for (int h = tid; h < 512; h += 256) hist[h] = 0u;

    float td0 = 3.4e38f, td1 = 3.4e38f, td2 = 3.4e38f, td3 = 3.4e38f;
    int ti0 = -1, ti1 = -1, ti2 = -1, ti3 = -1;

    for (int cc = 0; cc < C_CLUST / BN; ++cc) {
        float acc[8][8];
        #pragma unroll
        for (int i = 0; i < 8; ++i)
            #pragma unroll
            for (int j = 0; j < 8; ++j) acc[i][j] = 0.f;

        for (int kb = 0; kb < D_DIM / BK; ++kb) {
            __syncthreads();
            // stage A (transposed into LDS): 128 rows x 16 k
            #pragma unroll
            for (int i = 0; i < 2; ++i) {
                int q = tid + i * 256;       // 512 float4s
                int r = q >> 2;
                int kk = (q & 3) << 2;
                const float4 v = *reinterpret_cast<const float4*>(
                    &x[(rowBase + r) * D_DIM + kb * BK + kk]);
                As[(kk + 0) * BM + r] = v.x;
                As[(kk + 1) * BM + r] = v.y;
                As[(kk + 2) * BM + r] = v.z;
                As[(kk + 3) * BM + r] = v.w;
            }
            // stage B: 16 k x 128 clusters (dictT is [D][C])
            #pragma unroll
            for (int i = 0; i < 2; ++i) {
                int q = tid + i * 256;
                int k = q >> 5;
                int c4 = (q & 31) << 2;
                *reinterpret_cast<float4*>(&Bs[k * BN + c4]) =
                    *reinterpret_cast<const float4*>(
                        &dictT[(kb * BK + k) * C_CLUST + cc * BN + c4]);
            }
            __syncthreads();
            #pragma unroll
            for (int k = 0; k < BK; ++k) {
                float a[8], b[8];
                float4 t0 = *reinterpret_cast<const float4*>(&As[k * BM + ty * 8]);
                float4 t1 = *reinterpret_cast<const float4*>(&As[k * BM + ty * 8 + 4]);
                float4 u0 = *reinterpret_cast<const float4*>(&Bs[k * BN + tx * 8]);
                float4 u1 = *reinterpret_cast<const float4*>(&Bs[k * BN + tx * 8 + 4]);
                a[0]=t0.x; a[1]=t0.y; a[2]=t0.z; a[3]=t0.w;
                a[4]=t1.x; a[5]=t1.y; a[6]=t1.z; a[7]=t1.w;
                b[0]=u0.x; b[1]=u0.y; b[2]=u0.z; b[3]=u0.w;
                b[4]=u1.x; b[5]=u1.y; b[6]=u1.z; b[7]=u1.w;
                #pragma unroll
                for (int i = 0; i < 8; ++i)
                    #pragma unroll
                    for (int j = 0; j < 8; ++j)
                        acc[i][j] = fmaf(a[i], b[j], acc[i][j]);
            }
        }
        __syncthreads();
        // epilogue: S = (x^2 + d^2) - 2*dot  (match np association; no fma)
        {
            float ds[8];
            #pragma unroll
            for (int j = 0; j < 8; ++j) ds[j] = dsq[cc * BN + tx * 8 + j];
            #pragma unroll
            for (int i = 0; i < 8; ++i) {
                float xs = xsq[rowBase + ty * 8 + i];
                #pragma unroll
                for (int j = 0; j < 8; ++j) {
                    float v = __fsub_rn(__fadd_rn(xs, ds[j]),
                                        __fmul_rn(2.0f, acc[i][j]));
                    smem[(ty * 8 + i) * 129 + tx * 8 + j] = v;
                }
            }
        }
        __syncthreads();
        // top-4 merge: thread t owns row t (strict <, increasing idx => top_k ties)
        if (tid < BM) {
            const float* srow = &smem[tid * 129];
            #pragma unroll 4
            for (int c = 0; c < BN; ++c) {
                float v = srow[c];
                int idx = cc * BN + c;
                if (v < td3) {
                    if (v < td2) {
                        td3 = td2; ti3 = ti2;
                        if (v < td1) {
                            td2 = td1; ti2 = ti1;
                            if (v < td0) { td1 = td0; ti1 = ti0; td0 = v; ti0 = idx; }
                            else { td1 = v; ti1 = idx; }
                        } else { td2 = v; ti2 = idx; }
                    } else { td3 = v; ti3 = idx; }
                }
            }
        }
        __syncthreads();  // protect Stile until everyone finished scanning
    }

    if (tid < BM) {
        int r = rowBase + tid;
        out_topk[r * 4 + 0] = (float)ti0;
        out_topk[r * 4 + 1] = (float)ti1;
        out_topk[r * 4 + 2] = (float)ti2;
        out_topk[r * 4 + 3] = (float)ti3;
        atomicAdd(&hist[ti0], 1u);
        atomicAdd(&hist[ti1], 1u);
        atomicAdd(&hist[ti2], 1u);
        atomicAdd(&hist[ti3], 1u);
    }
    __syncthreads();
    for (int h = tid; h < 512; h += 256) {
        unsigned v = hist[h];
        if (v) atomicAdd(&counts[h], v);
    }
}

// ---------- K2: group_emb = mean of 4 dict rows, with STE rounding ----------
__global__ void group_emb_k(const float* __restrict__ x, const float* __restrict__ dic,
                            const float* __restrict__ topk, float* __restrict__ out)
{
    int row = blockIdx.x, d = threadIdx.x;
    int i0 = (int)topk[row * 4 + 0];
    int i1 = (int)topk[row * 4 + 1];
    int i2 = (int)topk[row * 4 + 2];
    int i3 = (int)topk[row * 4 + 3];
    float g = __fadd_rn(__fadd_rn(__fadd_rn(dic[i0 * D_DIM + d],
                                            dic[i1 * D_DIM + d]),
                                  dic[i2 * D_DIM + d]),
                        dic[i3 * D_DIM + d]);
    g = __fmul_rn(g, 0.25f);
    float xv = x[row * D_DIM + d];
    out[row * D_DIM + d] = __fadd_rn(__fsub_rn(g, xv), xv);
}

// ---------- K3: exclusive prefix sum of counts ----------
__global__ void prefix_k(const unsigned* __restrict__ counts, unsigned* __restrict__ offsets) {
    __shared__ unsigned s[512];
    int t = threadIdx.x;
    unsigned my = counts[t];
    s[t] = my;
    __syncthreads();
    for (int off = 1; off < 512; off <<= 1) {
        unsigned v = (t >= off) ? s[t - off] : 0u;
        __syncthreads();
        s[t] += v;
        __syncthreads();
    }
    offsets[t] = s[t] - my;
    if (t == 511) offsets[512] = s[511];
}

// ---------- K4: scatter rows into cluster buckets (packed (c<<16)|row) ----------
__global__ void scatter_k(const float* __restrict__ topk, const unsigned* __restrict__ offsets,
                          unsigned* __restrict__ fill, unsigned* __restrict__ rowlist) {
    int row = blockIdx.x * 256 + threadIdx.x;
    #pragma unroll
    for (int k = 0; k < 4; ++k) {
        int c = (int)topk[row * 4 + k];
        unsigned p = atomicAdd(&fill[c], 1u);
        rowlist[offsets[c] + p] = ((unsigned)c << 16) | (unsigned)row;
    }
}

// ---------- K5: load-balanced segmented sum (encodings^T @ X) ----------
// 2048 blocks x 128 rowlist entries each; thread d owns dim d; flush on
// cluster transition via float atomicAdd (isum pre-zeroed).
__global__ __launch_bounds__(256, 8) void cluster_sum2_k(
    const float* __restrict__ x, const unsigned* __restrict__ rowlist,
    float* __restrict__ isum)
{
    const int d = threadIdx.x;
    const int base = blockIdx.x * RPB;
    unsigned e0 = rowlist[base];
    int ccur = (int)(e0 >> 16);
    float acc = 0.f;
    #pragma unroll 4
    for (int j = 0; j < RPB; ++j) {
        unsigned e = rowlist[base + j];
        int c = (int)(e >> 16);
        float v = x[(e & 0xFFFFu) * D_DIM + d];
        if (c != ccur) {
            atomicAdd(&isum[ccur * D_DIM + d], acc);
            acc = 0.f;
            ccur = c;
        }
        acc += v;
    }
    atomicAdd(&isum[ccur * D_DIM + d], acc);
}

// ---------- K6: sequential decay scan + css EMA + laplace ----------
__global__ void ema_scalar_k(const float* __restrict__ css_in, const float* __restrict__ cnum_in,
                             const unsigned* __restrict__ counts,
                             float* __restrict__ ws, float* __restrict__ out) {
    __shared__ float sdecay[512];
    __shared__ float sred[512];
    __shared__ float scn[512];
    __shared__ unsigned smask[512];
    int t = threadIdx.x; // 512 threads
    unsigned cnt = counts[t];
    float size = (float)cnt;
    float mask = (cnt != 0u) ? 1.f : 0.f;
    float cnum_new = __fadd_rn(cnum_in[t], mask);
    scn[t] = cnum_new;
    smask[t] = cnt;
    __syncthreads();
    if (t == 0) {
        float d = 0.99f;
        for (int c = 0; c < 512; ++c) {
            if (smask[c] != 0u && scn[c] <= 10.0f)
                d = __fmul_rn(d, scn[c]) / 10.0f;   // (decay*c)/10, IEEE div
            sdecay[c] = d;
        }
    }
    __syncthreads();
    float d = sdecay[t];
    float css = css_in[t];
    float css_new = (cnt != 0u)
        ? __fadd_rn(__fmul_rn(css, d), __fmul_rn(size, __fsub_rn(1.f, d)))
        : css;
    out[OUT_CSS + t] = css_new;
    out[OUT_CNUM + t] = cnum_new;
    sred[t] = css_new;
    __syncthreads();
    for (int s = 256; s > 0; s >>= 1) {
        if (t < s) sred[t] += sred[t + s];
        __syncthreads();
    }
    float S = sred[0];
    float cs = __fmul_rn(__fdiv_rn(__fadd_rn(css_new, 1e-5f),
                                   __fadd_rn(S, 0.00512f)), S);
    ws[WS_CS + t] = cs;
    ws[WS_DCY + t] = d;
}

// ---------- K7: cluster_value EMA + dictionary normalize ----------
__global__ void final_k(const float* __restrict__ cv_in, const float* __restrict__ ws,
                        const unsigned* __restrict__ counts, float* __restrict__ out) {
    int c = blockIdx.x, d = threadIdx.x;
    float isum = ws[WS_ISUM + c * D_DIM + d];
    float dc = ws[WS_DCY + c];
    float cs = ws[WS_CS + c];
    unsigned cnt = counts[c];
    float cv = cv_in[c * D_DIM + d];
    float cvn = (cnt != 0u)
        ? __fadd_rn(__fmul_rn(cv, dc), __fmul_rn(isum, __fsub_rn(1.f, dc)))
        : cv;
    out[OUT_CV + c * D_DIM + d] = cvn;
    out[OUT_DICT + c * D_DIM + d] = (cnt != 0u) ? __fdiv_rn(cvn, cs) : cvn;
}

extern "C" void kernel_launch(void* const* d_in, const int* in_sizes, int n_in,
                              void* d_out, int out_size, void* d_ws, size_t ws_size,
                              hipStream_t stream) {
    const float* x       = (const float*)d_in[0];
    const float* dic     = (const float*)d_in[1];
    const float* css_in  = (const float*)d_in[2];
    const float* cv_in   = (const float*)d_in[3];
    const float* cnum_in = (const float*)d_in[4];
    float* out = (float*)d_out;
    float* ws  = (float*)d_ws;
    unsigned* counts  = (unsigned*)(ws + WS_COUNTS);
    unsigned* offsets = (unsigned*)(ws + WS_OFFSETS);
    unsigned* fill    = (unsigned*)(ws + WS_FILL);
    unsigned* rowlist = (unsigned*)(ws + WS_ROWLIST);

    zero_k<<<C_CLUST * D_DIM / 256, 256, 0, stream>>>(counts, fill, ws + WS_ISUM);
    prep_dict<<<C_CLUST, 256, 0, stream>>>(dic, ws);
    row_sq<<<N_ROWS, 256, 0, stream>>>(x, ws);

    size_t smem_bytes = 16512 * sizeof(float) + 512 * sizeof(unsigned);
    gemm_topk<<<N_ROWS / BM, 256, smem_bytes, stream>>>(x, ws, out + OUT_TOPK, counts);

    group_emb_k<<<N_ROWS, 256, 0, stream>>>(x, dic, out + OUT_TOPK, out + OUT_GEMB);
    prefix_k<<<1, 512, 0, stream>>>(counts, offsets);
    scatter_k<<<N_ROWS / 256, 256, 0, stream>>>(out + OUT_TOPK, offsets, fill, rowlist);
    cluster_sum2_k<<<N_ROWS * 4 / RPB, 256, 0, stream>>>(x, rowlist, ws + WS_ISUM);
    ema_scalar_k<<<1, 512, 0, stream>>>(css_in, cnum_in, counts, ws, out);
    final_k<<<C_CLUST, 256, 0, stream>>>(cv_in, ws, counts, out);
}